// Round 4
// baseline (490.879 us; speedup 1.0000x reference)
//
#include <hip/hip_runtime.h>
#include <stdint.h>

// MultiHeadAttentionShuffle: BS=4, SL=128, D=512, H=8, DP=64
// attn[b,t,h,q,k] = E[i,ik[k]] * F[i,t]  (i=idx_q[t,q]) for q<=t,k<=t;
//                 = 1/(t+1) for q>t,k<=t; 0 for k>t.
// R4: attn blocks handle 4 t-planes (stage E once); s_kernel emits S^T so ef's
// max/prefix-scan loops are coalesced.

#define BSZ 4
#define SLEN 128
#define DMODEL 512
#define NHEAD 8
#define HDIM 64

__device__ __forceinline__ uint32_t rotl32(uint32_t v, int d) {
  return (v << d) | (v >> (32 - d));
}

__device__ __forceinline__ void tf2x32(uint32_t k0, uint32_t k1, uint32_t x0,
                                       uint32_t x1, uint32_t& y0, uint32_t& y1) {
  uint32_t ks2 = k0 ^ k1 ^ 0x1BD11BDAu;
  x0 += k0; x1 += k1;
#define TF_R(r) { x0 += x1; x1 = rotl32(x1, (r)); x1 ^= x0; }
  TF_R(13) TF_R(15) TF_R(26) TF_R(6)
  x0 += k1;  x1 += ks2 + 1u;
  TF_R(17) TF_R(29) TF_R(16) TF_R(24)
  x0 += ks2; x1 += k0 + 2u;
  TF_R(13) TF_R(15) TF_R(26) TF_R(6)
  x0 += k0;  x1 += k1 + 3u;
  TF_R(17) TF_R(29) TF_R(16) TF_R(24)
  x0 += k1;  x1 += ks2 + 4u;
  TF_R(13) TF_R(15) TF_R(26) TF_R(6)
  x0 += ks2; x1 += k0 + 5u;
#undef TF_R
  y0 = x0; y1 = x1;
}

__device__ __forceinline__ uint16_t f32_to_bf16(float v) {
  uint32_t x = __float_as_uint(v);
  return (uint16_t)((x + 0x7FFFu + ((x >> 16) & 1u)) >> 16);
}
__device__ __forceinline__ float bf16_to_f32(uint16_t b) {
  return __uint_as_float(((uint32_t)b) << 16);
}

// ---------------- permutation indices (jax threefry partitionable) ----------------
__global__ __launch_bounds__(128) void idx_kernel(int* __restrict__ idx) {
  const int m = blockIdx.x;   // 0=q,1=k,2=v
  const int t = blockIdx.y;
  const int j = threadIdx.x;
  __shared__ float u[SLEN];
  uint32_t fk0, fk1;
  tf2x32(0u, 42u, 0u, (uint32_t)m, fk0, fk1);
  const int flat = t * SLEN + j;
  uint32_t y0, y1;
  tf2x32(fk0, fk1, 0u, (uint32_t)flat, y0, y1);
  uint32_t bits = y0 ^ y1;
  float uu = __uint_as_float((bits >> 9) | 0x3f800000u) - 1.0f;
  u[j] = uu;
  __syncthreads();
  int* row = idx + (m * SLEN + t) * SLEN;
  if (j >= t) {
    row[j] = j;
  } else {
    int rank = 0;
    for (int i = 0; i < t; ++i) {
      float ui = u[i];
      rank += ((ui < uu) || (ui == uu && i < j)) ? 1 : 0;
    }
    row[rank] = j;  // stable argsort
  }
}

// ------------- 512x512x512 fp32 GEMM, 64x64 tile, 128 thr, 4x8/thread -------------
__device__ __forceinline__ void gemm512_body(const float* __restrict__ A,
                                             const float* __restrict__ W,
                                             const float* __restrict__ bias,
                                             float* __restrict__ C,
                                             float* As /*16*68*/, float* Ws /*16*64*/) {
  const int tid = threadIdx.x;
  const int tx = tid & 7, ty = tid >> 3;      // 8 x 16
  const int row0 = blockIdx.y * 64, col0 = blockIdx.x * 64;
  const int ar = tid >> 1, ac = (tid & 1) * 8;   // A-tile: 64 rows x 16 cols
  const int wr = tid >> 3, wc = (tid & 7) * 8;   // W-tile: 16 rows x 64 cols
  float acc[4][8] = {};
  for (int k0 = 0; k0 < 512; k0 += 16) {
    float4 a0 = *(const float4*)(A + (size_t)(row0 + ar) * 512 + k0 + ac);
    float4 a1 = *(const float4*)(A + (size_t)(row0 + ar) * 512 + k0 + ac + 4);
    float4 w0 = *(const float4*)(W + (size_t)(k0 + wr) * 512 + col0 + wc);
    float4 w1 = *(const float4*)(W + (size_t)(k0 + wr) * 512 + col0 + wc + 4);
    As[(ac + 0) * 68 + ar] = a0.x; As[(ac + 1) * 68 + ar] = a0.y;
    As[(ac + 2) * 68 + ar] = a0.z; As[(ac + 3) * 68 + ar] = a0.w;
    As[(ac + 4) * 68 + ar] = a1.x; As[(ac + 5) * 68 + ar] = a1.y;
    As[(ac + 6) * 68 + ar] = a1.z; As[(ac + 7) * 68 + ar] = a1.w;
    *(float4*)(Ws + wr * 64 + wc) = w0;
    *(float4*)(Ws + wr * 64 + wc + 4) = w1;
    __syncthreads();
#pragma unroll
    for (int kk = 0; kk < 16; ++kk) {
      float4 a = *(const float4*)(As + kk * 68 + ty * 4);
      float4 b0 = *(const float4*)(Ws + kk * 64 + tx * 8);
      float4 b1 = *(const float4*)(Ws + kk * 64 + tx * 8 + 4);
      float av[4] = {a.x, a.y, a.z, a.w};
      float bv[8] = {b0.x, b0.y, b0.z, b0.w, b1.x, b1.y, b1.z, b1.w};
#pragma unroll
      for (int i = 0; i < 4; ++i)
#pragma unroll
        for (int jj = 0; jj < 8; ++jj) acc[i][jj] += av[i] * bv[jj];
    }
    __syncthreads();
  }
#pragma unroll
  for (int i = 0; i < 4; ++i) {
    int r = row0 + ty * 4 + i, c = col0 + tx * 8;
    float4 o0, o1;
    o0.x = acc[i][0] + bias[c + 0]; o0.y = acc[i][1] + bias[c + 1];
    o0.z = acc[i][2] + bias[c + 2]; o0.w = acc[i][3] + bias[c + 3];
    o1.x = acc[i][4] + bias[c + 4]; o1.y = acc[i][5] + bias[c + 5];
    o1.z = acc[i][6] + bias[c + 6]; o1.w = acc[i][7] + bias[c + 7];
    *(float4*)(C + (size_t)r * 512 + c) = o0;
    *(float4*)(C + (size_t)r * 512 + c + 4) = o1;
  }
}

__global__ __launch_bounds__(128) void proj_kernel(
    const float* __restrict__ q, const float* __restrict__ k, const float* __restrict__ v,
    const float* __restrict__ wq, const float* __restrict__ wk, const float* __restrict__ wv,
    const float* __restrict__ bq, const float* __restrict__ bk, const float* __restrict__ bv,
    float* __restrict__ qp, float* __restrict__ kp, float* __restrict__ vp) {
  __shared__ float As[16 * 68];
  __shared__ float Ws[16 * 64];
  const float* A; const float* W; const float* B; float* C;
  if (blockIdx.z == 0)      { A = q; W = wq; B = bq; C = qp; }
  else if (blockIdx.z == 1) { A = k; W = wk; B = bk; C = kp; }
  else                      { A = v; W = wv; B = bv; C = vp; }
  gemm512_body(A, W, B, C, As, Ws);
}

__global__ __launch_bounds__(128) void dense_kernel(const float* __restrict__ A,
                                                    const float* __restrict__ W,
                                                    const float* __restrict__ B,
                                                    float* __restrict__ C) {
  __shared__ float As[16 * 68];
  __shared__ float Ws[16 * 64];
  gemm512_body(A, W, B, C, As, Ws);
}

// ---------------- S[b,h,i,j] = dot(qp[b,i,h*64:], kp[b,j,h*64:]) / 8 ----------------
// Writes S (row-major) and S^T (for ef's coalesced max/scan).
__global__ __launch_bounds__(256) void s_kernel(const float* __restrict__ qp,
                                                const float* __restrict__ kp,
                                                float* __restrict__ S,
                                                float* __restrict__ ST) {
  const int h = blockIdx.x, b = blockIdx.y;
  const int tid = threadIdx.x;
  __shared__ float qs[32 * 132];
  __shared__ float ks[32 * 132];
  const float* qbase = qp + ((size_t)b * SLEN) * DMODEL + h * HDIM;
  const float* kbase = kp + ((size_t)b * SLEN) * DMODEL + h * HDIM;
  const int i0 = (tid >> 4) * 8, j0 = (tid & 15) * 8;
  float acc[8][8] = {};
  for (int d0 = 0; d0 < HDIM; d0 += 32) {
    __syncthreads();
    for (int it = 0; it < 4; ++it) {
      int flat = it * 256 + tid;          // 1024 float4 slots: 128 rows x 8
      int row = flat >> 3;
      int c4 = (flat & 7) << 2;
      float4 a = *(const float4*)(qbase + (size_t)row * DMODEL + d0 + c4);
      float4 bb = *(const float4*)(kbase + (size_t)row * DMODEL + d0 + c4);
      qs[(c4 + 0) * 132 + row] = a.x;  qs[(c4 + 1) * 132 + row] = a.y;
      qs[(c4 + 2) * 132 + row] = a.z;  qs[(c4 + 3) * 132 + row] = a.w;
      ks[(c4 + 0) * 132 + row] = bb.x; ks[(c4 + 1) * 132 + row] = bb.y;
      ks[(c4 + 2) * 132 + row] = bb.z; ks[(c4 + 3) * 132 + row] = bb.w;
    }
    __syncthreads();
    for (int d = 0; d < 32; ++d) {
      float4 qa = *(const float4*)(qs + d * 132 + i0);
      float4 qb = *(const float4*)(qs + d * 132 + i0 + 4);
      float4 ka = *(const float4*)(ks + d * 132 + j0);
      float4 kb = *(const float4*)(ks + d * 132 + j0 + 4);
      float a[8] = {qa.x, qa.y, qa.z, qa.w, qb.x, qb.y, qb.z, qb.w};
      float bb[8] = {ka.x, ka.y, ka.z, ka.w, kb.x, kb.y, kb.z, kb.w};
#pragma unroll
      for (int r = 0; r < 8; ++r)
#pragma unroll
        for (int c = 0; c < 8; ++c) acc[r][c] += a[r] * bb[c];
    }
  }
  float* Sb = S + (size_t)(b * NHEAD + h) * SLEN * SLEN;
  float* SbT = ST + (size_t)(b * NHEAD + h) * SLEN * SLEN;
#pragma unroll
  for (int r = 0; r < 8; ++r) {
    float4 o0, o1;
    o0.x = acc[r][0] * 0.125f; o0.y = acc[r][1] * 0.125f;
    o0.z = acc[r][2] * 0.125f; o0.w = acc[r][3] * 0.125f;
    o1.x = acc[r][4] * 0.125f; o1.y = acc[r][5] * 0.125f;
    o1.z = acc[r][6] * 0.125f; o1.w = acc[r][7] * 0.125f;
    *(float4*)(Sb + (size_t)(i0 + r) * SLEN + j0) = o0;
    *(float4*)(Sb + (size_t)(i0 + r) * SLEN + j0 + 4) = o1;
#pragma unroll
    for (int c = 0; c < 8; ++c)
      SbT[(size_t)(j0 + c) * SLEN + (i0 + r)] = acc[r][c] * 0.125f;
  }
}

// ------------- E[i,j]=bf16(exp(S-M127[i])); F[t,i]=exp(M127-M_t)/L_t -------------
// max/scan read S^T (coalesced: lane i reads ST[j*128+i]).
__global__ __launch_bounds__(128) void ef_kernel(const float* __restrict__ S,
                                                 const float* __restrict__ ST,
                                                 uint16_t* __restrict__ E,
                                                 float* __restrict__ Ft) {
  const int bh = blockIdx.x;   // 0..31
  const int i = threadIdx.x;   // row
  __shared__ float m127s[SLEN];
  const float* Sb = S + (size_t)bh * SLEN * SLEN;
  const float* SbT = ST + (size_t)bh * SLEN * SLEN;
  float m = -3.402823466e38f;
  for (int j = 0; j < SLEN; ++j) m = fmaxf(m, SbT[j * SLEN + i]);
  m127s[i] = m;
  float rm = -3.402823466e38f, rl = 0.f;
  float* Fb = Ft + (size_t)bh * SLEN * SLEN;  // [t][i]
  for (int t = 0; t < SLEN; ++t) {
    float sv = SbT[t * SLEN + i];
    float nm = fmaxf(rm, sv);
    rl = rl * __expf(rm - nm) + __expf(sv - nm);
    rm = nm;
    Fb[t * SLEN + i] = __expf(m - nm) / rl;
  }
  __syncthreads();
  uint16_t* Eb = E + (size_t)bh * SLEN * SLEN;
  for (int flat = i; flat < SLEN * SLEN; flat += SLEN) {
    int r = flat >> 7;
    Eb[flat] = f32_to_bf16(__expf(Sb[flat] - m127s[r]));
  }
}

// ------- attn writer: 4 t-planes per block, E staged once, store-bound -------
__global__ __launch_bounds__(256) void attn_kernel(const uint16_t* __restrict__ E,
                                                   const float* __restrict__ Ft,
                                                   const int* __restrict__ idx,
                                                   const float* __restrict__ vp,
                                                   float* __restrict__ attn_out,
                                                   float* __restrict__ eff) {
  const int h = blockIdx.x, g = blockIdx.y, b = blockIdx.z;
  const int tid = threadIdx.x;
  const int wave = tid >> 6, lane = tid & 63;
  __shared__ uint16_t Et[SLEN * SLEN];      // 32 KB
  __shared__ uint8_t iqs[4][SLEN], iks[4][SLEN], ivs[4][SLEN];
  __shared__ float Fs[4][SLEN];
  __shared__ float arow[SLEN];
  __shared__ float red[256];
  const int bh = b * NHEAD + h;
  const int tmax = 4 * g + 3;
  if (tid < SLEN) {
#pragma unroll
    for (int tt = 0; tt < 4; ++tt) {
      const int t = 4 * g + tt;
      iqs[tt][tid] = (uint8_t)idx[(0 * SLEN + t) * SLEN + tid];
      iks[tt][tid] = (uint8_t)idx[(1 * SLEN + t) * SLEN + tid];
      ivs[tt][tid] = (uint8_t)idx[(2 * SLEN + t) * SLEN + tid];
      Fs[tt][tid] = Ft[((size_t)bh * SLEN + t) * SLEN + tid];
    }
  }
  // stage E rows 0..tmax once for all 4 planes (bf16, coalesced; E is L2-resident)
  const uint16_t* Ebh = E + (size_t)bh * SLEN * SLEN;
  const int nsh = (tmax + 1) * SLEN;
  for (int off = tid * 4; off < nsh; off += 1024)
    *(ushort4*)(Et + off) = *(const ushort4*)(Ebh + off);
  __syncthreads();
  const int k0 = lane * 2, k1 = k0 + 1;
  for (int tt = 0; tt < 4; ++tt) {
    const int t = 4 * g + tt;
    const float inv = 1.0f / (float)(t + 1);
    float* obase = attn_out + ((size_t)((b * SLEN + t) * NHEAD + h)) * SLEN * SLEN;
    const int ik0 = iks[tt][k0], ik1 = iks[tt][k1];
    const bool k0ok = (k0 <= t), k1ok = (k1 <= t);
    for (int q = wave; q < SLEN; q += 4) {
      float2 val;
      if (q <= t) {
        int iq = iqs[tt][q];
        float f = Fs[tt][iq];
        val.x = k0ok ? bf16_to_f32(Et[iq * SLEN + ik0]) * f : 0.f;
        val.y = k1ok ? bf16_to_f32(Et[iq * SLEN + ik1]) * f : 0.f;
      } else {
        val.x = k0ok ? inv : 0.f;
        val.y = k1ok ? inv : 0.f;
      }
      *(float2*)(obase + (size_t)q * SLEN + k0) = val;
      if (q == t) { arow[k0] = val.x; arow[k1] = val.y; }
    }
    __syncthreads();
    // eff[b,t,h*64+d] = sum_{k<=t} arow[k] * vp[b, idx_v[t,k], h*64+d]
    {
      const int d = tid & 63, kg = tid >> 6;
      const float* vb = vp + (size_t)b * SLEN * DMODEL + h * HDIM + d;
      float acc = 0.f;
      for (int k = kg; k <= t; k += 4) acc += arow[k] * vb[(size_t)ivs[tt][k] * DMODEL];
      red[tid] = acc;
    }
    __syncthreads();
    if (tid < HDIM) {
      eff[((size_t)b * SLEN + t) * DMODEL + h * HDIM + tid] =
          red[tid] + red[tid + 64] + red[tid + 128] + red[tid + 192];
    }
    __syncthreads();  // protect arow before next plane's writes
  }
}

extern "C" void kernel_launch(void* const* d_in, const int* in_sizes, int n_in,
                              void* d_out, int out_size, void* d_ws, size_t ws_size,
                              hipStream_t stream) {
  const float* q    = (const float*)d_in[0];
  const float* k    = (const float*)d_in[1];
  const float* v    = (const float*)d_in[2];
  const float* wq_w = (const float*)d_in[4];
  const float* wq_b = (const float*)d_in[5];
  const float* wk_w = (const float*)d_in[6];
  const float* wk_b = (const float*)d_in[7];
  const float* wv_w = (const float*)d_in[8];
  const float* wv_b = (const float*)d_in[9];
  const float* dw   = (const float*)d_in[10];
  const float* db   = (const float*)d_in[11];

  float* out  = (float*)d_out;          // 4*128*512
  float* attn = out + 262144;           // 4*128*8*128*128

  // ws layout (float slots): E(bf16) | idx | qp | kp | vp | S | ST | Ft | eff
  float* wsf = (float*)d_ws;
  uint16_t* E = (uint16_t*)wsf;                    // 262144 slots
  int*   idx = (int*)(wsf + 262144);               // 49152
  float* qp  = wsf + 311296;
  float* kp  = qp + 262144;
  float* vp  = kp + 262144;
  float* S   = vp + 262144;                        // 524288
  float* ST  = S + 524288;                         // 524288
  float* Ft  = ST + 524288;                        // 524288
  float* eff = Ft + 524288;                        // 262144
  (void)in_sizes; (void)n_in; (void)out_size; (void)ws_size;

  idx_kernel<<<dim3(3, 128, 1), 128, 0, stream>>>(idx);
  proj_kernel<<<dim3(8, 8, 3), 128, 0, stream>>>(q, k, v, wq_w, wk_w, wv_w,
                                                 wq_b, wk_b, wv_b, qp, kp, vp);
  s_kernel<<<dim3(8, 4, 1), 256, 0, stream>>>(qp, kp, S, ST);
  ef_kernel<<<dim3(32, 1, 1), 128, 0, stream>>>(S, ST, E, Ft);
  attn_kernel<<<dim3(8, 32, 4), 256, 0, stream>>>(E, Ft, idx, vp, attn, eff);
  dense_kernel<<<dim3(8, 8, 1), 128, 0, stream>>>(eff, dw, db, out);
}

// Round 5
// 407.567 us; speedup vs baseline: 1.2044x; 1.2044x over previous
//
#include <hip/hip_runtime.h>
#include <stdint.h>

// MultiHeadAttentionShuffle: BS=4, SL=128, D=512, H=8, DP=64
// attn[b,t,h,q,k] = E[i,ik[k]] * F[i,t]  (i=idx_q[t,q]) for q<=t,k<=t;
//                 = 1/(t+1) for q>t,k<=t; 0 for k>t.
// R5: revert attn + GEMMs to the R2 structure (best measured); fuse s+ef into
// sef_kernel using F[t,i] = 1/prefixsum_{j<=t} exp(S[i,j]-m_i)  (no max-scan),
// so S never touches global memory. E gathers stay in global (L1/L2-resident;
// LDS staging measured as a regression in R3/R4).

#define BSZ 4
#define SLEN 128
#define DMODEL 512
#define NHEAD 8
#define HDIM 64

__device__ __forceinline__ uint32_t rotl32(uint32_t v, int d) {
  return (v << d) | (v >> (32 - d));
}

__device__ __forceinline__ void tf2x32(uint32_t k0, uint32_t k1, uint32_t x0,
                                       uint32_t x1, uint32_t& y0, uint32_t& y1) {
  uint32_t ks2 = k0 ^ k1 ^ 0x1BD11BDAu;
  x0 += k0; x1 += k1;
#define TF_R(r) { x0 += x1; x1 = rotl32(x1, (r)); x1 ^= x0; }
  TF_R(13) TF_R(15) TF_R(26) TF_R(6)
  x0 += k1;  x1 += ks2 + 1u;
  TF_R(17) TF_R(29) TF_R(16) TF_R(24)
  x0 += ks2; x1 += k0 + 2u;
  TF_R(13) TF_R(15) TF_R(26) TF_R(6)
  x0 += k0;  x1 += k1 + 3u;
  TF_R(17) TF_R(29) TF_R(16) TF_R(24)
  x0 += k1;  x1 += ks2 + 4u;
  TF_R(13) TF_R(15) TF_R(26) TF_R(6)
  x0 += ks2; x1 += k0 + 5u;
#undef TF_R
  y0 = x0; y1 = x1;
}

__device__ __forceinline__ uint16_t f32_to_bf16(float v) {
  uint32_t x = __float_as_uint(v);
  return (uint16_t)((x + 0x7FFFu + ((x >> 16) & 1u)) >> 16);
}
__device__ __forceinline__ float bf16_to_f32(uint16_t b) {
  return __uint_as_float(((uint32_t)b) << 16);
}

// ---------------- permutation indices (jax threefry partitionable) ----------------
__global__ __launch_bounds__(128) void idx_kernel(int* __restrict__ idx) {
  const int m = blockIdx.x;   // 0=q,1=k,2=v
  const int t = blockIdx.y;
  const int j = threadIdx.x;
  __shared__ float u[SLEN];
  uint32_t fk0, fk1;
  tf2x32(0u, 42u, 0u, (uint32_t)m, fk0, fk1);
  const int flat = t * SLEN + j;
  uint32_t y0, y1;
  tf2x32(fk0, fk1, 0u, (uint32_t)flat, y0, y1);
  uint32_t bits = y0 ^ y1;
  float uu = __uint_as_float((bits >> 9) | 0x3f800000u) - 1.0f;
  u[j] = uu;
  __syncthreads();
  int* row = idx + (m * SLEN + t) * SLEN;
  if (j >= t) {
    row[j] = j;
  } else {
    int rank = 0;
    for (int i = 0; i < t; ++i) {
      float ui = u[i];
      rank += ((ui < uu) || (ui == uu && i < j)) ? 1 : 0;
    }
    row[rank] = j;  // stable argsort
  }
}

// ---------------- 512x512x512 fp32 GEMM (R2 shape: 256 thr, 4x4/thread) ----------------
__device__ __forceinline__ void gemm512_body(const float* __restrict__ A,
                                             const float* __restrict__ W,
                                             const float* __restrict__ bias,
                                             float* __restrict__ C,
                                             float* As /*64*17*/, float* Ws /*16*64*/) {
  const int tid = threadIdx.x;
  const int tx = tid & 15, ty = tid >> 4;
  const int row0 = blockIdx.y * 64, col0 = blockIdx.x * 64;
  const int lr = tid >> 2, lc = (tid & 3) << 2;   // A-tile load coords (64x16)
  const int wr = tid >> 4, wc = (tid & 15) << 2;  // W-tile load coords (16x64)
  float acc[4][4] = {};
  for (int k0 = 0; k0 < 512; k0 += 16) {
    float4 av = *(const float4*)(A + (size_t)(row0 + lr) * 512 + k0 + lc);
    float4 wv = *(const float4*)(W + (size_t)(k0 + wr) * 512 + col0 + wc);
    As[lr * 17 + lc + 0] = av.x; As[lr * 17 + lc + 1] = av.y;
    As[lr * 17 + lc + 2] = av.z; As[lr * 17 + lc + 3] = av.w;
    *(float4*)(Ws + wr * 64 + wc) = wv;
    __syncthreads();
#pragma unroll
    for (int kk = 0; kk < 16; ++kk) {
      float a[4], b[4];
#pragma unroll
      for (int i = 0; i < 4; ++i) a[i] = As[(ty * 4 + i) * 17 + kk];
#pragma unroll
      for (int jj = 0; jj < 4; ++jj) b[jj] = Ws[kk * 64 + tx * 4 + jj];
#pragma unroll
      for (int i = 0; i < 4; ++i)
#pragma unroll
        for (int jj = 0; jj < 4; ++jj) acc[i][jj] += a[i] * b[jj];
    }
    __syncthreads();
  }
#pragma unroll
  for (int i = 0; i < 4; ++i) {
    int r = row0 + ty * 4 + i, c = col0 + tx * 4;
    float4 o;
    o.x = acc[i][0] + bias[c + 0];
    o.y = acc[i][1] + bias[c + 1];
    o.z = acc[i][2] + bias[c + 2];
    o.w = acc[i][3] + bias[c + 3];
    *(float4*)(C + (size_t)r * 512 + c) = o;
  }
}

__global__ __launch_bounds__(256) void proj_kernel(
    const float* __restrict__ q, const float* __restrict__ k, const float* __restrict__ v,
    const float* __restrict__ wq, const float* __restrict__ wk, const float* __restrict__ wv,
    const float* __restrict__ bq, const float* __restrict__ bk, const float* __restrict__ bv,
    float* __restrict__ qp, float* __restrict__ kp, float* __restrict__ vp) {
  __shared__ float As[64 * 17];
  __shared__ float Ws[16 * 64];
  const float* A; const float* W; const float* B; float* C;
  if (blockIdx.z == 0)      { A = q; W = wq; B = bq; C = qp; }
  else if (blockIdx.z == 1) { A = k; W = wk; B = bk; C = kp; }
  else                      { A = v; W = wv; B = bv; C = vp; }
  gemm512_body(A, W, B, C, As, Ws);
}

__global__ __launch_bounds__(256) void dense_kernel(const float* __restrict__ A,
                                                    const float* __restrict__ W,
                                                    const float* __restrict__ B,
                                                    float* __restrict__ C) {
  __shared__ float As[64 * 17];
  __shared__ float Ws[16 * 64];
  gemm512_body(A, W, B, C, As, Ws);
}

// ------------- fused S + softmax factors: E (bf16) and F, S stays on-chip -------------
// S[i,j] = dot(qp_i, kp_j)/8;  m_i = row max;  E[i,j] = exp(S-m_i) (bf16 to global);
// F[t,i] = 1 / prefixsum_{j<=t} exp(S[i,j]-m_i)  (fp32 prefix of E-values).
__global__ __launch_bounds__(256) void sef_kernel(const float* __restrict__ qp,
                                                  const float* __restrict__ kp,
                                                  uint16_t* __restrict__ E,
                                                  float* __restrict__ Ft) {
  const int h = blockIdx.x, b = blockIdx.y;
  const int tid = threadIdx.x;
  __shared__ float qs[32 * 132];
  __shared__ float ks[32 * 132];
  __shared__ float redm[128 * 16];   // per (row, jgroup) partial max
  __shared__ float csum[128 * 16];   // per (row, jgroup) exp-sum
  __shared__ float m127s[SLEN];
  const float* qbase = qp + ((size_t)b * SLEN) * DMODEL + h * HDIM;
  const float* kbase = kp + ((size_t)b * SLEN) * DMODEL + h * HDIM;
  const int i0 = (tid >> 4) * 8, jg = tid & 15, j0 = jg * 8;
  float acc[8][8] = {};
  for (int d0 = 0; d0 < HDIM; d0 += 32) {
    __syncthreads();
    for (int it = 0; it < 4; ++it) {
      int flat = it * 256 + tid;          // 1024 float4 slots: 128 rows x 8
      int row = flat >> 3;
      int c4 = (flat & 7) << 2;
      float4 a = *(const float4*)(qbase + (size_t)row * DMODEL + d0 + c4);
      float4 bb = *(const float4*)(kbase + (size_t)row * DMODEL + d0 + c4);
      qs[(c4 + 0) * 132 + row] = a.x;  qs[(c4 + 1) * 132 + row] = a.y;
      qs[(c4 + 2) * 132 + row] = a.z;  qs[(c4 + 3) * 132 + row] = a.w;
      ks[(c4 + 0) * 132 + row] = bb.x; ks[(c4 + 1) * 132 + row] = bb.y;
      ks[(c4 + 2) * 132 + row] = bb.z; ks[(c4 + 3) * 132 + row] = bb.w;
    }
    __syncthreads();
    for (int d = 0; d < 32; ++d) {
      float4 qa = *(const float4*)(qs + d * 132 + i0);
      float4 qb = *(const float4*)(qs + d * 132 + i0 + 4);
      float4 ka = *(const float4*)(ks + d * 132 + j0);
      float4 kb = *(const float4*)(ks + d * 132 + j0 + 4);
      float a[8] = {qa.x, qa.y, qa.z, qa.w, qb.x, qb.y, qb.z, qb.w};
      float bb[8] = {ka.x, ka.y, ka.z, ka.w, kb.x, kb.y, kb.z, kb.w};
#pragma unroll
      for (int r = 0; r < 8; ++r)
#pragma unroll
        for (int c = 0; c < 8; ++c) acc[r][c] += a[r] * bb[c];
    }
  }
  // scale to S and per-thread partial row maxes
#pragma unroll
  for (int r = 0; r < 8; ++r) {
    float m = -3.402823466e38f;
#pragma unroll
    for (int c = 0; c < 8; ++c) {
      acc[r][c] *= 0.125f;
      m = fmaxf(m, acc[r][c]);
    }
    redm[(i0 + r) * 16 + jg] = m;
  }
  __syncthreads();
  if (tid < SLEN) {
    float m = redm[tid * 16];
#pragma unroll
    for (int g = 1; g < 16; ++g) m = fmaxf(m, redm[tid * 16 + g]);
    m127s[tid] = m;
  }
  __syncthreads();
  const int bh = b * NHEAD + h;
  uint16_t* Eb = E + (size_t)bh * SLEN * SLEN;
  // exp, write E (bf16), build thread-local prefix in acc
#pragma unroll
  for (int r = 0; r < 8; ++r) {
    const float m = m127s[i0 + r];
    float run = 0.f;
    ushort4 e0, e1;
    float ev;
    ev = __expf(acc[r][0] - m); e0.x = f32_to_bf16(ev); run += ev; acc[r][0] = run;
    ev = __expf(acc[r][1] - m); e0.y = f32_to_bf16(ev); run += ev; acc[r][1] = run;
    ev = __expf(acc[r][2] - m); e0.z = f32_to_bf16(ev); run += ev; acc[r][2] = run;
    ev = __expf(acc[r][3] - m); e0.w = f32_to_bf16(ev); run += ev; acc[r][3] = run;
    ev = __expf(acc[r][4] - m); e1.x = f32_to_bf16(ev); run += ev; acc[r][4] = run;
    ev = __expf(acc[r][5] - m); e1.y = f32_to_bf16(ev); run += ev; acc[r][5] = run;
    ev = __expf(acc[r][6] - m); e1.z = f32_to_bf16(ev); run += ev; acc[r][6] = run;
    ev = __expf(acc[r][7] - m); e1.w = f32_to_bf16(ev); run += ev; acc[r][7] = run;
    *(ushort4*)(Eb + (size_t)(i0 + r) * SLEN + j0) = e0;
    *(ushort4*)(Eb + (size_t)(i0 + r) * SLEN + j0 + 4) = e1;
    csum[(i0 + r) * 16 + jg] = run;
  }
  __syncthreads();
  // cross-group exclusive prefix + F writes: F[t][i] = 1/(base + local_prefix)
  float* Fb = Ft + (size_t)bh * SLEN * SLEN;
#pragma unroll
  for (int r = 0; r < 8; ++r) {
    float base = 0.f;
    for (int g = 0; g < 16; ++g) {
      if (g == jg) break;
      base += csum[(i0 + r) * 16 + g];
    }
#pragma unroll
    for (int c = 0; c < 8; ++c)
      Fb[(size_t)(j0 + c) * SLEN + (i0 + r)] = 1.0f / (base + acc[r][c]);
  }
}

// ------------- attn writer (R2 structure): global bf16 E gathers + fused eff -------------
__global__ __launch_bounds__(256) void attn_kernel(const uint16_t* __restrict__ E,
                                                   const float* __restrict__ Ft,
                                                   const int* __restrict__ idx,
                                                   const float* __restrict__ vp,
                                                   float* __restrict__ attn_out,
                                                   float* __restrict__ eff) {
  const int h = blockIdx.x, t = blockIdx.y, b = blockIdx.z;
  const int tid = threadIdx.x;
  const int wave = tid >> 6, lane = tid & 63;
  __shared__ int iqs[SLEN], iks[SLEN], ivs[SLEN];
  __shared__ float Fs[SLEN];
  __shared__ float arow[SLEN];
  __shared__ float red[256];
  const int bh = b * NHEAD + h;
  if (tid < SLEN) {
    iqs[tid] = idx[(0 * SLEN + t) * SLEN + tid];
    iks[tid] = idx[(1 * SLEN + t) * SLEN + tid];
    ivs[tid] = idx[(2 * SLEN + t) * SLEN + tid];
    Fs[tid] = Ft[((size_t)bh * SLEN + t) * SLEN + tid];
  }
  __syncthreads();
  const uint16_t* Eb = E + (size_t)bh * SLEN * SLEN;
  const float inv = 1.0f / (float)(t + 1);
  float* obase = attn_out + ((size_t)((b * SLEN + t) * NHEAD + h)) * SLEN * SLEN;
  const int k0 = lane * 2, k1 = k0 + 1;
  const int ik0 = iks[k0], ik1 = iks[k1];
  const bool k0ok = (k0 <= t), k1ok = (k1 <= t);
  for (int q = wave; q < SLEN; q += 4) {
    float2 val;
    if (q <= t) {
      int iq = iqs[q];
      float f = Fs[iq];
      const uint16_t* Er = Eb + (size_t)iq * SLEN;
      val.x = k0ok ? bf16_to_f32(Er[ik0]) * f : 0.f;
      val.y = k1ok ? bf16_to_f32(Er[ik1]) * f : 0.f;
    } else {
      val.x = k0ok ? inv : 0.f;
      val.y = k1ok ? inv : 0.f;
    }
    *(float2*)(obase + (size_t)q * SLEN + k0) = val;
    if (q == t) { arow[k0] = val.x; arow[k1] = val.y; }
  }
  __syncthreads();
  // eff[b,t,h*64+d] = sum_{k<=t} arow[k] * vp[b, idx_v[t,k], h*64+d], 4-way k-split
  {
    const int d = tid & 63, kg = tid >> 6;
    const float* vb = vp + (size_t)b * SLEN * DMODEL + h * HDIM + d;
    float acc = 0.f;
    for (int k = kg; k <= t; k += 4) acc += arow[k] * vb[(size_t)ivs[k] * DMODEL];
    red[tid] = acc;
  }
  __syncthreads();
  if (tid < HDIM) {
    eff[((size_t)b * SLEN + t) * DMODEL + h * HDIM + tid] =
        red[tid] + red[tid + 64] + red[tid + 128] + red[tid + 192];
  }
}

extern "C" void kernel_launch(void* const* d_in, const int* in_sizes, int n_in,
                              void* d_out, int out_size, void* d_ws, size_t ws_size,
                              hipStream_t stream) {
  const float* q    = (const float*)d_in[0];
  const float* k    = (const float*)d_in[1];
  const float* v    = (const float*)d_in[2];
  const float* wq_w = (const float*)d_in[4];
  const float* wq_b = (const float*)d_in[5];
  const float* wk_w = (const float*)d_in[6];
  const float* wk_b = (const float*)d_in[7];
  const float* wv_w = (const float*)d_in[8];
  const float* wv_b = (const float*)d_in[9];
  const float* dw   = (const float*)d_in[10];
  const float* db   = (const float*)d_in[11];

  float* out  = (float*)d_out;          // 4*128*512
  float* attn = out + 262144;           // 4*128*8*128*128

  // ws layout (float slots): E(bf16) | idx | qp | kp | vp | Ft | eff
  float* wsf = (float*)d_ws;
  uint16_t* E = (uint16_t*)wsf;                    // 262144 slots
  int*   idx = (int*)(wsf + 262144);               // 49152
  float* qp  = wsf + 311296;
  float* kp  = qp + 262144;
  float* vp  = kp + 262144;
  float* Ft  = vp + 262144;                        // 524288
  float* eff = Ft + 524288;                        // 262144
  (void)in_sizes; (void)n_in; (void)out_size; (void)ws_size;

  idx_kernel<<<dim3(3, 128, 1), 128, 0, stream>>>(idx);
  proj_kernel<<<dim3(8, 8, 3), 256, 0, stream>>>(q, k, v, wq_w, wk_w, wv_w,
                                                 wq_b, wk_b, wv_b, qp, kp, vp);
  sef_kernel<<<dim3(8, 4, 1), 256, 0, stream>>>(qp, kp, E, Ft);
  attn_kernel<<<dim3(8, 128, 4), 256, 0, stream>>>(E, Ft, idx, vp, attn, eff);
  dense_kernel<<<dim3(8, 8, 1), 256, 0, stream>>>(eff, dw, db, out);
}

// Round 6
// 398.051 us; speedup vs baseline: 1.2332x; 1.0239x over previous
//
#include <hip/hip_runtime.h>
#include <stdint.h>

// MultiHeadAttentionShuffle: BS=4, SL=128, D=512, H=8, DP=64
// attn[b,t,h,q,k] = E[i,ik[k]] * F[i,t]  (i=idx_q[t,q]) for q<=t,k<=t;
//                 = 1/(t+1) for q>t,k<=t; 0 for k>t.
// R6: attn inner loop -> 4 k per lane (float4 stores, 2 q-rows/wave-iter,
// halved issue count). Rest identical to R5 (best: 407.6 us).

#define BSZ 4
#define SLEN 128
#define DMODEL 512
#define NHEAD 8
#define HDIM 64

__device__ __forceinline__ uint32_t rotl32(uint32_t v, int d) {
  return (v << d) | (v >> (32 - d));
}

__device__ __forceinline__ void tf2x32(uint32_t k0, uint32_t k1, uint32_t x0,
                                       uint32_t x1, uint32_t& y0, uint32_t& y1) {
  uint32_t ks2 = k0 ^ k1 ^ 0x1BD11BDAu;
  x0 += k0; x1 += k1;
#define TF_R(r) { x0 += x1; x1 = rotl32(x1, (r)); x1 ^= x0; }
  TF_R(13) TF_R(15) TF_R(26) TF_R(6)
  x0 += k1;  x1 += ks2 + 1u;
  TF_R(17) TF_R(29) TF_R(16) TF_R(24)
  x0 += ks2; x1 += k0 + 2u;
  TF_R(13) TF_R(15) TF_R(26) TF_R(6)
  x0 += k0;  x1 += k1 + 3u;
  TF_R(17) TF_R(29) TF_R(16) TF_R(24)
  x0 += k1;  x1 += ks2 + 4u;
  TF_R(13) TF_R(15) TF_R(26) TF_R(6)
  x0 += ks2; x1 += k0 + 5u;
#undef TF_R
  y0 = x0; y1 = x1;
}

__device__ __forceinline__ uint16_t f32_to_bf16(float v) {
  uint32_t x = __float_as_uint(v);
  return (uint16_t)((x + 0x7FFFu + ((x >> 16) & 1u)) >> 16);
}
__device__ __forceinline__ float bf16_to_f32(uint16_t b) {
  return __uint_as_float(((uint32_t)b) << 16);
}

// ---------------- permutation indices (jax threefry partitionable) ----------------
__global__ __launch_bounds__(128) void idx_kernel(int* __restrict__ idx) {
  const int m = blockIdx.x;   // 0=q,1=k,2=v
  const int t = blockIdx.y;
  const int j = threadIdx.x;
  __shared__ float u[SLEN];
  uint32_t fk0, fk1;
  tf2x32(0u, 42u, 0u, (uint32_t)m, fk0, fk1);
  const int flat = t * SLEN + j;
  uint32_t y0, y1;
  tf2x32(fk0, fk1, 0u, (uint32_t)flat, y0, y1);
  uint32_t bits = y0 ^ y1;
  float uu = __uint_as_float((bits >> 9) | 0x3f800000u) - 1.0f;
  u[j] = uu;
  __syncthreads();
  int* row = idx + (m * SLEN + t) * SLEN;
  if (j >= t) {
    row[j] = j;
  } else {
    int rank = 0;
    for (int i = 0; i < t; ++i) {
      float ui = u[i];
      rank += ((ui < uu) || (ui == uu && i < j)) ? 1 : 0;
    }
    row[rank] = j;  // stable argsort
  }
}

// ---------------- 512x512x512 fp32 GEMM (R2 shape: 256 thr, 4x4/thread) ----------------
__device__ __forceinline__ void gemm512_body(const float* __restrict__ A,
                                             const float* __restrict__ W,
                                             const float* __restrict__ bias,
                                             float* __restrict__ C,
                                             float* As /*64*17*/, float* Ws /*16*64*/) {
  const int tid = threadIdx.x;
  const int tx = tid & 15, ty = tid >> 4;
  const int row0 = blockIdx.y * 64, col0 = blockIdx.x * 64;
  const int lr = tid >> 2, lc = (tid & 3) << 2;   // A-tile load coords (64x16)
  const int wr = tid >> 4, wc = (tid & 15) << 2;  // W-tile load coords (16x64)
  float acc[4][4] = {};
  for (int k0 = 0; k0 < 512; k0 += 16) {
    float4 av = *(const float4*)(A + (size_t)(row0 + lr) * 512 + k0 + lc);
    float4 wv = *(const float4*)(W + (size_t)(k0 + wr) * 512 + col0 + wc);
    As[lr * 17 + lc + 0] = av.x; As[lr * 17 + lc + 1] = av.y;
    As[lr * 17 + lc + 2] = av.z; As[lr * 17 + lc + 3] = av.w;
    *(float4*)(Ws + wr * 64 + wc) = wv;
    __syncthreads();
#pragma unroll
    for (int kk = 0; kk < 16; ++kk) {
      float a[4], b[4];
#pragma unroll
      for (int i = 0; i < 4; ++i) a[i] = As[(ty * 4 + i) * 17 + kk];
#pragma unroll
      for (int jj = 0; jj < 4; ++jj) b[jj] = Ws[kk * 64 + tx * 4 + jj];
#pragma unroll
      for (int i = 0; i < 4; ++i)
#pragma unroll
        for (int jj = 0; jj < 4; ++jj) acc[i][jj] += a[i] * b[jj];
    }
    __syncthreads();
  }
#pragma unroll
  for (int i = 0; i < 4; ++i) {
    int r = row0 + ty * 4 + i, c = col0 + tx * 4;
    float4 o;
    o.x = acc[i][0] + bias[c + 0];
    o.y = acc[i][1] + bias[c + 1];
    o.z = acc[i][2] + bias[c + 2];
    o.w = acc[i][3] + bias[c + 3];
    *(float4*)(C + (size_t)r * 512 + c) = o;
  }
}

__global__ __launch_bounds__(256) void proj_kernel(
    const float* __restrict__ q, const float* __restrict__ k, const float* __restrict__ v,
    const float* __restrict__ wq, const float* __restrict__ wk, const float* __restrict__ wv,
    const float* __restrict__ bq, const float* __restrict__ bk, const float* __restrict__ bv,
    float* __restrict__ qp, float* __restrict__ kp, float* __restrict__ vp) {
  __shared__ float As[64 * 17];
  __shared__ float Ws[16 * 64];
  const float* A; const float* W; const float* B; float* C;
  if (blockIdx.z == 0)      { A = q; W = wq; B = bq; C = qp; }
  else if (blockIdx.z == 1) { A = k; W = wk; B = bk; C = kp; }
  else                      { A = v; W = wv; B = bv; C = vp; }
  gemm512_body(A, W, B, C, As, Ws);
}

__global__ __launch_bounds__(256) void dense_kernel(const float* __restrict__ A,
                                                    const float* __restrict__ W,
                                                    const float* __restrict__ B,
                                                    float* __restrict__ C) {
  __shared__ float As[64 * 17];
  __shared__ float Ws[16 * 64];
  gemm512_body(A, W, B, C, As, Ws);
}

// ------------- fused S + softmax factors: E (bf16) and F, S stays on-chip -------------
__global__ __launch_bounds__(256) void sef_kernel(const float* __restrict__ qp,
                                                  const float* __restrict__ kp,
                                                  uint16_t* __restrict__ E,
                                                  float* __restrict__ Ft) {
  const int h = blockIdx.x, b = blockIdx.y;
  const int tid = threadIdx.x;
  __shared__ float qs[32 * 132];
  __shared__ float ks[32 * 132];
  __shared__ float redm[128 * 16];   // per (row, jgroup) partial max
  __shared__ float csum[128 * 16];   // per (row, jgroup) exp-sum
  __shared__ float m127s[SLEN];
  const float* qbase = qp + ((size_t)b * SLEN) * DMODEL + h * HDIM;
  const float* kbase = kp + ((size_t)b * SLEN) * DMODEL + h * HDIM;
  const int i0 = (tid >> 4) * 8, jg = tid & 15, j0 = jg * 8;
  float acc[8][8] = {};
  for (int d0 = 0; d0 < HDIM; d0 += 32) {
    __syncthreads();
    for (int it = 0; it < 4; ++it) {
      int flat = it * 256 + tid;          // 1024 float4 slots: 128 rows x 8
      int row = flat >> 3;
      int c4 = (flat & 7) << 2;
      float4 a = *(const float4*)(qbase + (size_t)row * DMODEL + d0 + c4);
      float4 bb = *(const float4*)(kbase + (size_t)row * DMODEL + d0 + c4);
      qs[(c4 + 0) * 132 + row] = a.x;  qs[(c4 + 1) * 132 + row] = a.y;
      qs[(c4 + 2) * 132 + row] = a.z;  qs[(c4 + 3) * 132 + row] = a.w;
      ks[(c4 + 0) * 132 + row] = bb.x; ks[(c4 + 1) * 132 + row] = bb.y;
      ks[(c4 + 2) * 132 + row] = bb.z; ks[(c4 + 3) * 132 + row] = bb.w;
    }
    __syncthreads();
    for (int d = 0; d < 32; ++d) {
      float4 qa = *(const float4*)(qs + d * 132 + i0);
      float4 qb = *(const float4*)(qs + d * 132 + i0 + 4);
      float4 ka = *(const float4*)(ks + d * 132 + j0);
      float4 kb = *(const float4*)(ks + d * 132 + j0 + 4);
      float a[8] = {qa.x, qa.y, qa.z, qa.w, qb.x, qb.y, qb.z, qb.w};
      float bb[8] = {ka.x, ka.y, ka.z, ka.w, kb.x, kb.y, kb.z, kb.w};
#pragma unroll
      for (int r = 0; r < 8; ++r)
#pragma unroll
        for (int c = 0; c < 8; ++c) acc[r][c] += a[r] * bb[c];
    }
  }
#pragma unroll
  for (int r = 0; r < 8; ++r) {
    float m = -3.402823466e38f;
#pragma unroll
    for (int c = 0; c < 8; ++c) {
      acc[r][c] *= 0.125f;
      m = fmaxf(m, acc[r][c]);
    }
    redm[(i0 + r) * 16 + jg] = m;
  }
  __syncthreads();
  if (tid < SLEN) {
    float m = redm[tid * 16];
#pragma unroll
    for (int g = 1; g < 16; ++g) m = fmaxf(m, redm[tid * 16 + g]);
    m127s[tid] = m;
  }
  __syncthreads();
  const int bh = b * NHEAD + h;
  uint16_t* Eb = E + (size_t)bh * SLEN * SLEN;
#pragma unroll
  for (int r = 0; r < 8; ++r) {
    const float m = m127s[i0 + r];
    float run = 0.f;
    ushort4 e0, e1;
    float ev;
    ev = __expf(acc[r][0] - m); e0.x = f32_to_bf16(ev); run += ev; acc[r][0] = run;
    ev = __expf(acc[r][1] - m); e0.y = f32_to_bf16(ev); run += ev; acc[r][1] = run;
    ev = __expf(acc[r][2] - m); e0.z = f32_to_bf16(ev); run += ev; acc[r][2] = run;
    ev = __expf(acc[r][3] - m); e0.w = f32_to_bf16(ev); run += ev; acc[r][3] = run;
    ev = __expf(acc[r][4] - m); e1.x = f32_to_bf16(ev); run += ev; acc[r][4] = run;
    ev = __expf(acc[r][5] - m); e1.y = f32_to_bf16(ev); run += ev; acc[r][5] = run;
    ev = __expf(acc[r][6] - m); e1.z = f32_to_bf16(ev); run += ev; acc[r][6] = run;
    ev = __expf(acc[r][7] - m); e1.w = f32_to_bf16(ev); run += ev; acc[r][7] = run;
    *(ushort4*)(Eb + (size_t)(i0 + r) * SLEN + j0) = e0;
    *(ushort4*)(Eb + (size_t)(i0 + r) * SLEN + j0 + 4) = e1;
    csum[(i0 + r) * 16 + jg] = run;
  }
  __syncthreads();
  float* Fb = Ft + (size_t)bh * SLEN * SLEN;
#pragma unroll
  for (int r = 0; r < 8; ++r) {
    float base = 0.f;
    for (int g = 0; g < 16; ++g) {
      if (g == jg) break;
      base += csum[(i0 + r) * 16 + g];
    }
#pragma unroll
    for (int c = 0; c < 8; ++c)
      Fb[(size_t)(j0 + c) * SLEN + (i0 + r)] = 1.0f / (base + acc[r][c]);
  }
}

// ------------- attn writer: 4 k/lane, float4 stores, 2 q-rows per wave-iter -------------
__global__ __launch_bounds__(256) void attn_kernel(const uint16_t* __restrict__ E,
                                                   const float* __restrict__ Ft,
                                                   const int* __restrict__ idx,
                                                   const float* __restrict__ vp,
                                                   float* __restrict__ attn_out,
                                                   float* __restrict__ eff) {
  const int h = blockIdx.x, t = blockIdx.y, b = blockIdx.z;
  const int tid = threadIdx.x;
  const int wave = tid >> 6, lane = tid & 63;
  const int half = lane >> 5;          // which of the 2 q-rows this lane covers
  const int l32 = lane & 31;
  __shared__ int iqs[SLEN], iks[SLEN], ivs[SLEN];
  __shared__ float Fs[SLEN];
  __shared__ float arow[SLEN];
  __shared__ float red[256];
  const int bh = b * NHEAD + h;
  if (tid < SLEN) {
    iqs[tid] = idx[(0 * SLEN + t) * SLEN + tid];
    iks[tid] = idx[(1 * SLEN + t) * SLEN + tid];
    ivs[tid] = idx[(2 * SLEN + t) * SLEN + tid];
    Fs[tid] = Ft[((size_t)bh * SLEN + t) * SLEN + tid];
  }
  __syncthreads();
  const uint16_t* Eb = E + (size_t)bh * SLEN * SLEN;
  const float inv = 1.0f / (float)(t + 1);
  float* obase = attn_out + ((size_t)((b * SLEN + t) * NHEAD + h)) * SLEN * SLEN;
  const int k0 = l32 * 4;
  const int ikA = iks[k0], ikB = iks[k0 + 1], ikC = iks[k0 + 2], ikD = iks[k0 + 3];
  float4 cm;   // causal k-mask for this lane's 4 columns
  cm.x = (k0 + 0 <= t) ? 1.f : 0.f;
  cm.y = (k0 + 1 <= t) ? 1.f : 0.f;
  cm.z = (k0 + 2 <= t) ? 1.f : 0.f;
  cm.w = (k0 + 3 <= t) ? 1.f : 0.f;
#pragma unroll 2
  for (int q8 = wave * 2; q8 < SLEN; q8 += 8) {
    const int qe = q8 + half;   // this half-wave's q-row
    float4 val;
    if (qe <= t) {
      const int iq = iqs[qe];
      const float f = Fs[iq];
      const uint16_t* Er = Eb + (size_t)iq * SLEN;
      val.x = bf16_to_f32(Er[ikA]) * f * cm.x;
      val.y = bf16_to_f32(Er[ikB]) * f * cm.y;
      val.z = bf16_to_f32(Er[ikC]) * f * cm.z;
      val.w = bf16_to_f32(Er[ikD]) * f * cm.w;
    } else {
      val.x = inv * cm.x; val.y = inv * cm.y;
      val.z = inv * cm.z; val.w = inv * cm.w;
    }
    *(float4*)(obase + (size_t)qe * SLEN + k0) = val;
    if (qe == t) *(float4*)(arow + k0) = val;
  }
  __syncthreads();
  // eff[b,t,h*64+d] = sum_{k<=t} arow[k] * vp[b, idx_v[t,k], h*64+d], 4-way k-split
  {
    const int d = tid & 63, kg = tid >> 6;
    const float* vb = vp + (size_t)b * SLEN * DMODEL + h * HDIM + d;
    float acc = 0.f;
    for (int k = kg; k <= t; k += 4) acc += arow[k] * vb[(size_t)ivs[k] * DMODEL];
    red[tid] = acc;
  }
  __syncthreads();
  if (tid < HDIM) {
    eff[((size_t)b * SLEN + t) * DMODEL + h * HDIM + tid] =
        red[tid] + red[tid + 64] + red[tid + 128] + red[tid + 192];
  }
}

extern "C" void kernel_launch(void* const* d_in, const int* in_sizes, int n_in,
                              void* d_out, int out_size, void* d_ws, size_t ws_size,
                              hipStream_t stream) {
  const float* q    = (const float*)d_in[0];
  const float* k    = (const float*)d_in[1];
  const float* v    = (const float*)d_in[2];
  const float* wq_w = (const float*)d_in[4];
  const float* wq_b = (const float*)d_in[5];
  const float* wk_w = (const float*)d_in[6];
  const float* wk_b = (const float*)d_in[7];
  const float* wv_w = (const float*)d_in[8];
  const float* wv_b = (const float*)d_in[9];
  const float* dw   = (const float*)d_in[10];
  const float* db   = (const float*)d_in[11];

  float* out  = (float*)d_out;          // 4*128*512
  float* attn = out + 262144;           // 4*128*8*128*128

  // ws layout (float slots): E(bf16) | idx | qp | kp | vp | Ft | eff
  float* wsf = (float*)d_ws;
  uint16_t* E = (uint16_t*)wsf;                    // 262144 slots
  int*   idx = (int*)(wsf + 262144);               // 49152
  float* qp  = wsf + 311296;
  float* kp  = qp + 262144;
  float* vp  = kp + 262144;
  float* Ft  = vp + 262144;                        // 524288
  float* eff = Ft + 524288;                        // 262144
  (void)in_sizes; (void)n_in; (void)out_size; (void)ws_size;

  idx_kernel<<<dim3(3, 128, 1), 128, 0, stream>>>(idx);
  proj_kernel<<<dim3(8, 8, 3), 256, 0, stream>>>(q, k, v, wq_w, wk_w, wv_w,
                                                 wq_b, wk_b, wv_b, qp, kp, vp);
  sef_kernel<<<dim3(8, 4, 1), 256, 0, stream>>>(qp, kp, E, Ft);
  attn_kernel<<<dim3(8, 128, 4), 256, 0, stream>>>(E, Ft, idx, vp, attn, eff);
  dense_kernel<<<dim3(8, 8, 1), 256, 0, stream>>>(eff, dw, db, out);
}